// Round 13
// baseline (3152.737 us; speedup 1.0000x reference)
//
#include <hip/hip_runtime.h>
#include <cstdint>

#define NPTS 8192
#define NBATCH 4
#define NS 2048
#define NK 32
#define CIN 64
#define C0 67   // 3 + 64
#define H1 64
#define H2 64
#define H3 128
#define CAP 1024
#define BIGF 1e10f
#define NCONS 124          // consumer blocks (grid = 4 + NCONS = 128; 1.6x throughput margin)

// ws layout in floats
#define WT0_OFF 0        // 67*64
#define B0_OFF  4288     // 64
#define WT1_OFF 4352     // 64*64
#define B1_OFF  8448     // 64
#define WT2_OFF 8512     // 64*128
#define B2_OFF  16704    // 128
#define PROG_OFF 16832   // 4 counters, 64-int (256B) spaced
#define STAGE_OFF 17088  // float4[NBATCH*NS] staging (16B aligned)

// shared-memory union offsets (bytes)
#define P_LCO 0          // producer: 8192 * float4 = 131072
#define P_CND 131072     // producer: 2*4*2 floats = 64
#define C_CAND 0         // consumer: 1024 * u64 = 8192
#define C_HA   8192      // 32*69*4 = 8832
#define C_HB   17024     // 32*65*4 = 8320
#define C_SEL  25344     // 32*4
#define C_CNT  25488     // 4
#define C_CXY  25504     // float4 (16B aligned)
#define SMEM_BYTES 131200

typedef float f32x2 __attribute__((ext_vector_type(2)));
typedef float f32x4 __attribute__((ext_vector_type(4)));

__device__ __forceinline__ float sq3(float ax, float ay, float az) {
  // exact f32, no contraction: (ax*ax + ay*ay) + az*az
  return __fadd_rn(__fadd_rn(__fmul_rn(ax, ax), __fmul_rn(ay, ay)), __fmul_rn(az, az));
}

// ---- cache-bypass (sc0 sc1 -> coherence point = L3/mem, shared across XCDs) ----
__device__ __forceinline__ void bypass_store128(void* p, f32x4 v) {
  asm volatile("global_store_dwordx4 %0, %1, off sc0 sc1" :: "v"(p), "v"(v) : "memory");
}
__device__ __forceinline__ f32x4 bypass_load128(const void* p) {
  f32x4 r;
  asm volatile("global_load_dwordx4 %0, %1, off sc0 sc1\n\ts_waitcnt vmcnt(0)"
               : "=v"(r) : "v"(p) : "memory");
  return r;
}
__device__ __forceinline__ void bypass_store32(void* p, int v) {
  asm volatile("global_store_dword %0, %1, off sc0 sc1" :: "v"(p), "v"(v) : "memory");
}
__device__ __forceinline__ int bypass_load32(const void* p) {
  int r;
  asm volatile("global_load_dword %0, %1, off sc0 sc1\n\ts_waitcnt vmcnt(0)"
               : "=v"(r) : "v"(p) : "memory");
  return r;
}

// packed 2xf32 ops (VOP3P, IEEE f32 per lane — exact, same as scalar __f*_rn)
__device__ __forceinline__ f32x2 pk_sub(f32x2 a, f32x2 b) {
  f32x2 r;
  asm("v_pk_add_f32 %0, %1, %2 neg_lo:[0,1] neg_hi:[0,1]" : "=v"(r) : "v"(a), "v"(b));
  return r;
}
__device__ __forceinline__ f32x2 pk_mul(f32x2 a, f32x2 b) {
  f32x2 r;
  asm("v_pk_mul_f32 %0, %1, %2" : "=v"(r) : "v"(a), "v"(b));
  return r;
}
__device__ __forceinline__ f32x2 pk_add(f32x2 a, f32x2 b) {
  f32x2 r;
  asm("v_pk_add_f32 %0, %1, %2" : "=v"(r) : "v"(a), "v"(b));
  return r;
}

// Lexicographic (max d, tie -> min idx) pair-combine with a DPP-shuffled copy.
#define PAIRRED(dv, iv, ctrl)                                                          \
  {                                                                                    \
    int _sd = __builtin_amdgcn_update_dpp(__float_as_int(dv), __float_as_int(dv),      \
                                          (ctrl), 0xf, 0xf, false);                    \
    int _si = __builtin_amdgcn_update_dpp((iv), (iv), (ctrl), 0xf, 0xf, false);        \
    float _fd = __int_as_float(_sd);                                                   \
    bool _tk = (_fd > (dv)) || ((_fd == (dv)) && (_si < (iv)));                        \
    (dv) = _tk ? _fd : (dv);                                                           \
    (iv) = _tk ? _si : (iv);                                                           \
  }

// ---------------- fold BN into weights (transposed [c][o]) ----------------
__global__ void fold_kernel(const float* __restrict__ W0, const float* __restrict__ g0, const float* __restrict__ be0, const float* __restrict__ m0, const float* __restrict__ v0,
                            const float* __restrict__ W1, const float* __restrict__ g1, const float* __restrict__ be1, const float* __restrict__ m1, const float* __restrict__ v1,
                            const float* __restrict__ W2, const float* __restrict__ g2, const float* __restrict__ be2, const float* __restrict__ m2, const float* __restrict__ v2,
                            float* __restrict__ ws) {
  int t = blockIdx.x * 256 + threadIdx.x;
  if (t < C0 * H1) {
    int c = t / H1, o = t - c * H1;
    float sc = g0[o] / sqrtf(v0[o] + 1e-5f);
    ws[WT0_OFF + t] = W0[o * C0 + c] * sc;
  } else if (t < B0_OFF + H1) {
    int o = t - B0_OFF;
    float sc = g0[o] / sqrtf(v0[o] + 1e-5f);
    ws[t] = be0[o] - m0[o] * sc;
  } else if (t < WT1_OFF + H1 * H2) {
    int t2 = t - WT1_OFF; int c = t2 / H2, o = t2 - c * H2;
    float sc = g1[o] / sqrtf(v1[o] + 1e-5f);
    ws[t] = W1[o * H1 + c] * sc;
  } else if (t < B1_OFF + H2) {
    int o = t - B1_OFF;
    float sc = g1[o] / sqrtf(v1[o] + 1e-5f);
    ws[t] = be1[o] - m1[o] * sc;
  } else if (t < WT2_OFF + H2 * H3) {
    int t2 = t - WT2_OFF; int c = t2 / H3, o = t2 - c * H3;
    float sc = g2[o] / sqrtf(v2[o] + 1e-5f);
    ws[t] = W2[o * H2 + c] * sc;
  } else if (t < B2_OFF + H3) {
    int o = t - B2_OFF;
    float sc = g2[o] / sqrtf(v2[o] + 1e-5f);
    ws[t] = be2[o] - m2[o] * sc;
  }
}

// ---------------- fused: blocks 0-3 = FPS producer, rest = SA consumers ----------------
__global__ __launch_bounds__(256, 1)
void fused_kernel(const float* __restrict__ xyz, const float* __restrict__ feat,
                  const float* __restrict__ ws, float* __restrict__ newxyz,
                  float* __restrict__ outf, int* __restrict__ prog,
                  f32x4* __restrict__ stage) {
  __shared__ __align__(16) char smem[SMEM_BYTES];
  const int blk = blockIdx.x;
  const int tid = threadIdx.x;
  const int lane = tid & 63;

  if (blk < NBATCH) {
    // =========================== PRODUCER (FPS) ===========================
    const int b = blk;
    const float* px = xyz + (size_t)b * NPTS * 3;
    const int wv = tid >> 6;   // 0..3
    float* lco = (float*)(smem + P_LCO);
    float (*cnd)[4][2] = (float(*)[4][2])(smem + P_CND);
    int* pb = prog + b * 64;   // 256B-spaced progress counter

    f32x2 X2[16], Y2[16], Z2[16], D2[16];
#pragma unroll
    for (int jj = 0; jj < 16; ++jj) {
      int p0 = tid * 32 + 2 * jj;
      float x0 = px[p0 * 3 + 0], y0 = px[p0 * 3 + 1], z0 = px[p0 * 3 + 2];
      float x1 = px[p0 * 3 + 3], y1 = px[p0 * 3 + 4], z1 = px[p0 * 3 + 5];
      X2[jj][0] = x0; X2[jj][1] = x1;
      Y2[jj][0] = y0; Y2[jj][1] = y1;
      Z2[jj][0] = z0; Z2[jj][1] = z1;
      D2[jj][0] = BIGF; D2[jj][1] = BIGF;
      *(float4*)&lco[(size_t)p0 * 4]       = make_float4(x0, y0, z0, 0.0f);
      *(float4*)&lco[(size_t)(p0 + 1) * 4] = make_float4(x1, y1, z1, 0.0f);
    }

    float cx = px[0], cy = px[1], cz = px[2];
    // wave-0 register capture slots (lane l holds centroid of iter with t&15==l)
    float sx = cx, sy = cy, sz = cz;   // lane 0 -> t=0 centroid
    if (tid == 0) {
      float* o = newxyz + (size_t)b * NS * 3;
      o[0] = cx; o[1] = cy; o[2] = cz;
    }
    __syncthreads();   // lco ready

    int par = 0;
    for (int t = 1; t < NS; ++t) {
      f32x2 cpx, cpy, cpz;
      cpx[0] = cx; cpx[1] = cx;
      cpy[0] = cy; cpy[1] = cy;
      cpz[0] = cz; cpz[1] = cz;
      float bd = -1.0f; int bi = 0;
#pragma unroll
      for (int jj = 0; jj < 16; ++jj) {
        f32x2 dx = pk_sub(X2[jj], cpx);
        f32x2 dy = pk_sub(Y2[jj], cpy);
        f32x2 dz = pk_sub(Z2[jj], cpz);
        f32x2 xx = pk_mul(dx, dx);
        f32x2 yy = pk_mul(dy, dy);
        f32x2 ss = pk_add(xx, yy);
        f32x2 zz = pk_mul(dz, dz);
        f32x2 dd = pk_add(ss, zz);
        float n0 = fminf(D2[jj][0], dd[0]);
        float n1 = fminf(D2[jj][1], dd[1]);
        D2[jj][0] = n0; D2[jj][1] = n1;
        bool g0 = n0 > bd;
        bd = g0 ? n0 : bd;
        bi = g0 ? (tid * 32 + 2 * jj) : bi;
        bool g1 = n1 > bd;
        bd = g1 ? n1 : bd;
        bi = g1 ? (tid * 32 + 2 * jj + 1) : bi;
      }
      PAIRRED(bd, bi, 0x121);
      PAIRRED(bd, bi, 0x122);
      PAIRRED(bd, bi, 0x124);
      PAIRRED(bd, bi, 0x128);
      PAIRRED(bd, bi, 0x142);
      PAIRRED(bd, bi, 0x143);   // lane63 = wave winner
      if (lane == 63) {
        cnd[par][wv][0] = bd;
        cnd[par][wv][1] = __int_as_float(bi);
      }
      __syncthreads();

      const int ci = lane & 3;
      f32x2 cc = *(const f32x2*)&cnd[par][ci][0];
      float pd = cc[0];
      int pi = __float_as_int(cc[1]);
      PAIRRED(pd, pi, 0x121);
      PAIRRED(pd, pi, 0x122);
      const int far = __builtin_amdgcn_readfirstlane(pi);
      float4 c4 = *(const float4*)&lco[(size_t)far * 4];
      cx = c4.x; cy = c4.y; cz = c4.z;
      if (tid == 0) {
        float* o = newxyz + ((size_t)b * NS + t) * 3;   // plain L2 stores (R9-proven)
        o[0] = cx; o[1] = cy; o[2] = cz;
      }
      if (wv == 0) {
        // capture into the matching lane's registers (2-3 VALU ops, no memory)
        bool cap = (lane < 16) && (lane == (t & 15));
        sx = cap ? cx : sx; sy = cap ? cy : sy; sz = cap ? cz : sz;
        if ((t & 15) == 15) {
          // LAGGED publish: cover the PREVIOUS interval (its stores were issued
          // 16 iters (~18us, ~43k cycles) ago -> certainly retired). No drain.
          if (lane == 0) bypass_store32(pb, t - 15);
          if (lane < 16) {
            f32x4 st; st[0] = sx; st[1] = sy; st[2] = sz; st[3] = 0.0f;
            bypass_store128(stage + (size_t)b * NS + (t - 15) + lane, st);
          }
        }
      }
      par ^= 1;
    }
    // final: drain all stage stores, then publish completion
    if (wv == 0) {
      asm volatile("s_waitcnt vmcnt(0)" ::: "memory");
      if (lane == 0) bypass_store32(pb, NS);
    }
  } else {
    // =========================== CONSUMERS (SA) ===========================
    unsigned long long* cand = (unsigned long long*)(smem + C_CAND);
    float* hA = (float*)(smem + C_HA);
    float* hB = (float*)(smem + C_HB);
    int* sel = (int*)(smem + C_SEL);
    int* cntp = (int*)(smem + C_CNT);
    float* cxyz = (float*)(smem + C_CXY);

    int seen = 0;

    // tile mapping g -> (b = g&3, s = g>>2): each consumer's batch is FIXED
    // (NCONS/4 pollers per prog line), batches consumed evenly as produced.
    for (int g = blk - NBATCH; g < NBATCH * NS; g += NCONS) {
      const int b = g & 3;
      const int s = g >> 2;
      const size_t srow = (size_t)b * NS + s;

      if (tid == 0) {
        *cntp = 0;
        if (seen <= s) {
          int pv;
          do {
            pv = bypass_load32(prog + b * 64);
            if (pv <= s) __builtin_amdgcn_s_sleep(32);
          } while (pv <= s);
          seen = pv;
        }
        f32x4 c4 = bypass_load128(stage + srow);
        cxyz[0] = c4[0]; cxyz[1] = c4[1]; cxyz[2] = c4[2];
      }
      __syncthreads();

      const float* px = xyz + (size_t)b * NPTS * 3;
      const float* pf = feat + (size_t)b * NPTS * CIN;
      const float cx = cxyz[0];
      const float cy = cxyz[1];
      const float cz = cxyz[2];

      // ---- phase A: ball query + ballot compaction ----
      const float ssrc = sq3(cx, cy, cz);
      const float R2F = 0.04f;  // f32 round of f64 0.2**2
      for (int p = tid; p < NPTS; p += 256) {
        float x = px[p * 3 + 0], y = px[p * 3 + 1], z = px[p * 3 + 2];
        float sdst = sq3(x, y, z);
        float dot = __fadd_rn(__fadd_rn(__fmul_rn(cx, x), __fmul_rn(cy, y)), __fmul_rn(cz, z));
        float d = __fsub_rn(__fadd_rn(ssrc, sdst), __fmul_rn(2.0f, dot));
        d = fmaxf(d, 0.0f);
        bool hit = (d <= R2F);
        unsigned long long m = __ballot(hit);
        if (m) {
          int base = 0;
          if (lane == 0) base = atomicAdd(cntp, __popcll(m));
          base = __shfl(base, 0);
          if (hit) {
            int pos = base + __popcll(m & ((1ull << lane) - 1ull));
            if (pos < CAP)
              cand[pos] = ((unsigned long long)__float_as_uint(d) << 32) | (unsigned long long)(unsigned)p;
          }
        }
      }
      __syncthreads();

      // ---- phase B: parallel rank-select of 32 smallest ----
      {
        const int cnt = min(*cntp, CAP);
        if (cnt <= 256) {
          unsigned long long k0 = (tid < cnt) ? cand[tid] : ~0ull;
          int r0 = 0;
          int j = 0;
          for (; j + 2 <= cnt; j += 2) {
            ulonglong2 kj = *(const ulonglong2*)&cand[j];
            r0 += (kj.x < k0) ? 1 : 0;
            r0 += (kj.y < k0) ? 1 : 0;
          }
          if (j < cnt) r0 += (cand[j] < k0) ? 1 : 0;
          if (tid < cnt) {
            if (r0 < NK) sel[r0] = (int)(k0 & 0xffffffffull);
            if (r0 == 0) {
              for (int q = cnt; q < NK; ++q) sel[q] = (int)(k0 & 0xffffffffull);
            }
          }
        } else if (cnt <= 512) {
          unsigned long long k0 = cand[tid];
          unsigned long long k1 = (256 + tid < cnt) ? cand[256 + tid] : ~0ull;
          int r0 = 0, r1 = 0;
          int j = 0;
          for (; j + 2 <= cnt; j += 2) {
            ulonglong2 kj = *(const ulonglong2*)&cand[j];
            r0 += (kj.x < k0) ? 1 : 0; r0 += (kj.y < k0) ? 1 : 0;
            r1 += (kj.x < k1) ? 1 : 0; r1 += (kj.y < k1) ? 1 : 0;
          }
          if (j < cnt) { unsigned long long kj = cand[j]; r0 += (kj < k0) ? 1 : 0; r1 += (kj < k1) ? 1 : 0; }
          if (r0 < NK) sel[r0] = (int)(k0 & 0xffffffffull);
          if (256 + tid < cnt && r1 < NK) sel[r1] = (int)(k1 & 0xffffffffull);
        } else {
          unsigned long long k0 = cand[tid];
          unsigned long long k1 = cand[256 + tid];
          unsigned long long k2 = (512 + tid < cnt) ? cand[512 + tid] : ~0ull;
          unsigned long long k3 = (768 + tid < cnt) ? cand[768 + tid] : ~0ull;
          int r0 = 0, r1 = 0, r2 = 0, r3 = 0;
          int j = 0;
          for (; j + 2 <= cnt; j += 2) {
            ulonglong2 kj = *(const ulonglong2*)&cand[j];
            r0 += (kj.x < k0) ? 1 : 0; r0 += (kj.y < k0) ? 1 : 0;
            r1 += (kj.x < k1) ? 1 : 0; r1 += (kj.y < k1) ? 1 : 0;
            r2 += (kj.x < k2) ? 1 : 0; r2 += (kj.y < k2) ? 1 : 0;
            r3 += (kj.x < k3) ? 1 : 0; r3 += (kj.y < k3) ? 1 : 0;
          }
          if (j < cnt) {
            unsigned long long kj = cand[j];
            r0 += (kj < k0) ? 1 : 0; r1 += (kj < k1) ? 1 : 0;
            r2 += (kj < k2) ? 1 : 0; r3 += (kj < k3) ? 1 : 0;
          }
          if (r0 < NK) sel[r0] = (int)(k0 & 0xffffffffull);
          if (r1 < NK) sel[r1] = (int)(k1 & 0xffffffffull);
          if (512 + tid < cnt && r2 < NK) sel[r2] = (int)(k2 & 0xffffffffull);
          if (768 + tid < cnt && r3 < NK) sel[r3] = (int)(k3 & 0xffffffffull);
        }
      }
      __syncthreads();

      // ---- phase C: build h0 = [centered xyz(3) | feat(64)] into hA [32][69] ----
      {
        int kk = tid >> 3, j = tid & 7;
        int ip = sel[kk];
        const float* fr = pf + (size_t)ip * CIN + j * 8;
        float4 a = *(const float4*)(fr);
        float4 c4 = *(const float4*)(fr + 4);
        float* hrow = hA + kk * 69 + 3 + j * 8;
        hrow[0] = a.x;  hrow[1] = a.y;  hrow[2] = a.z;  hrow[3] = a.w;
        hrow[4] = c4.x; hrow[5] = c4.y; hrow[6] = c4.z; hrow[7] = c4.w;
      }
      if (tid < 32) {
        int ip = sel[tid];
        hA[tid * 69 + 0] = px[ip * 3 + 0] - cx;
        hA[tid * 69 + 1] = px[ip * 3 + 1] - cy;
        hA[tid * 69 + 2] = px[ip * 3 + 2] - cz;
      }
      __syncthreads();

      const int k = tid & 31;
      const int ob = tid >> 5;

      // ---- layer 1: 67 -> 64 ----
      {
        const float* Wt = ws + WT0_OFF;
        const float* bb = ws + B0_OFF;
        const int o0 = ob * 8;
        float acc[8];
#pragma unroll
        for (int i = 0; i < 8; ++i) acc[i] = bb[o0 + i];
        const float* hrow = hA + k * 69;
        for (int c = 0; c < C0; ++c) {
          float h = hrow[c];
          const float4 w0 = *(const float4*)(Wt + c * H1 + o0);
          const float4 w1 = *(const float4*)(Wt + c * H1 + o0 + 4);
          acc[0] = fmaf(h, w0.x, acc[0]); acc[1] = fmaf(h, w0.y, acc[1]);
          acc[2] = fmaf(h, w0.z, acc[2]); acc[3] = fmaf(h, w0.w, acc[3]);
          acc[4] = fmaf(h, w1.x, acc[4]); acc[5] = fmaf(h, w1.y, acc[5]);
          acc[6] = fmaf(h, w1.z, acc[6]); acc[7] = fmaf(h, w1.w, acc[7]);
        }
        float* orow = hB + k * 65 + o0;
#pragma unroll
        for (int i = 0; i < 8; ++i) orow[i] = fmaxf(acc[i], 0.0f);
      }
      __syncthreads();

      // ---- layer 2: 64 -> 64 (hB -> hA, stride 65) ----
      {
        const float* Wt = ws + WT1_OFF;
        const float* bb = ws + B1_OFF;
        const int o0 = ob * 8;
        float acc[8];
#pragma unroll
        for (int i = 0; i < 8; ++i) acc[i] = bb[o0 + i];
        const float* hrow = hB + k * 65;
        for (int c = 0; c < H1; ++c) {
          float h = hrow[c];
          const float4 w0 = *(const float4*)(Wt + c * H2 + o0);
          const float4 w1 = *(const float4*)(Wt + c * H2 + o0 + 4);
          acc[0] = fmaf(h, w0.x, acc[0]); acc[1] = fmaf(h, w0.y, acc[1]);
          acc[2] = fmaf(h, w0.z, acc[2]); acc[3] = fmaf(h, w0.w, acc[3]);
          acc[4] = fmaf(h, w1.x, acc[4]); acc[5] = fmaf(h, w1.y, acc[5]);
          acc[6] = fmaf(h, w1.z, acc[6]); acc[7] = fmaf(h, w1.w, acc[7]);
        }
        float* orow = hA + k * 65 + o0;
#pragma unroll
        for (int i = 0; i < 8; ++i) orow[i] = fmaxf(acc[i], 0.0f);
      }
      __syncthreads();

      // ---- layer 3: 64 -> 128 + max over neighbors ----
      {
        const float* Wt = ws + WT2_OFF;
        const float* bb = ws + B2_OFF;
        const int o0 = ob * 16;
        float acc[16];
#pragma unroll
        for (int i = 0; i < 16; ++i) acc[i] = bb[o0 + i];
        const float* hrow = hA + k * 65;
        for (int c = 0; c < H2; ++c) {
          float h = hrow[c];
          const float4 w0 = *(const float4*)(Wt + c * H3 + o0);
          const float4 w1 = *(const float4*)(Wt + c * H3 + o0 + 4);
          const float4 w2 = *(const float4*)(Wt + c * H3 + o0 + 8);
          const float4 w3 = *(const float4*)(Wt + c * H3 + o0 + 12);
          acc[0]  = fmaf(h, w0.x, acc[0]);  acc[1]  = fmaf(h, w0.y, acc[1]);
          acc[2]  = fmaf(h, w0.z, acc[2]);  acc[3]  = fmaf(h, w0.w, acc[3]);
          acc[4]  = fmaf(h, w1.x, acc[4]);  acc[5]  = fmaf(h, w1.y, acc[5]);
          acc[6]  = fmaf(h, w1.z, acc[6]);  acc[7]  = fmaf(h, w1.w, acc[7]);
          acc[8]  = fmaf(h, w2.x, acc[8]);  acc[9]  = fmaf(h, w2.y, acc[9]);
          acc[10] = fmaf(h, w2.z, acc[10]); acc[11] = fmaf(h, w2.w, acc[11]);
          acc[12] = fmaf(h, w3.x, acc[12]); acc[13] = fmaf(h, w3.y, acc[13]);
          acc[14] = fmaf(h, w3.z, acc[14]); acc[15] = fmaf(h, w3.w, acc[15]);
        }
#pragma unroll
        for (int i = 0; i < 16; ++i) acc[i] = fmaxf(acc[i], 0.0f);
#pragma unroll
        for (int m = 1; m < 32; m <<= 1) {
#pragma unroll
          for (int i = 0; i < 16; ++i) {
            float o = __shfl_xor(acc[i], m);
            acc[i] = fmaxf(acc[i], o);
          }
        }
        if (k == 0) {
          float* op = outf + srow * H3 + o0;
          *(float4*)(op + 0)  = make_float4(acc[0],  acc[1],  acc[2],  acc[3]);
          *(float4*)(op + 4)  = make_float4(acc[4],  acc[5],  acc[6],  acc[7]);
          *(float4*)(op + 8)  = make_float4(acc[8],  acc[9],  acc[10], acc[11]);
          *(float4*)(op + 12) = make_float4(acc[12], acc[13], acc[14], acc[15]);
        }
      }
      __syncthreads();
    }
  }
}

extern "C" void kernel_launch(void* const* d_in, const int* in_sizes, int n_in,
                              void* d_out, int out_size, void* d_ws, size_t ws_size,
                              hipStream_t stream) {
  const float* xyz  = (const float*)d_in[0];
  const float* feat = (const float*)d_in[1];
  const float* W0 = (const float*)d_in[2];
  const float* g0 = (const float*)d_in[3];
  const float* be0 = (const float*)d_in[4];
  const float* m0 = (const float*)d_in[5];
  const float* v0 = (const float*)d_in[6];
  const float* W1 = (const float*)d_in[7];
  const float* g1 = (const float*)d_in[8];
  const float* be1 = (const float*)d_in[9];
  const float* m1 = (const float*)d_in[10];
  const float* v1 = (const float*)d_in[11];
  const float* W2 = (const float*)d_in[12];
  const float* g2 = (const float*)d_in[13];
  const float* be2 = (const float*)d_in[14];
  const float* m2 = (const float*)d_in[15];
  const float* v2 = (const float*)d_in[16];

  float* out = (float*)d_out;               // [B,S,3] then [B,S,128]
  float* wsf = (float*)d_ws;
  int* prog = (int*)(wsf + PROG_OFF);
  f32x4* stage = (f32x4*)(wsf + STAGE_OFF);
  float* outfeat = out + (size_t)NBATCH * NS * 3;

  fold_kernel<<<(B2_OFF + H3 + 255) / 256, 256, 0, stream>>>(
      W0, g0, be0, m0, v0, W1, g1, be1, m1, v1, W2, g2, be2, m2, v2, wsf);
  hipMemsetAsync(prog, 0, NBATCH * 64 * sizeof(int), stream);   // reset progress each launch
  fused_kernel<<<NBATCH + NCONS, 256, 0, stream>>>(xyz, feat, wsf, out, outfeat, prog, stage);
}

// Round 14
// 2301.568 us; speedup vs baseline: 1.3698x; 1.3698x over previous
//
#include <hip/hip_runtime.h>
#include <cstdint>

#define NPTS 8192
#define NBATCH 4
#define NS 2048
#define NK 32
#define CIN 64
#define C0 67   // 3 + 64
#define H1 64
#define H2 64
#define H3 128
#define CAP 1024
#define BIGF 1e10f
#define NCONS 248          // consumer blocks (grid = 252; 124 was consumer-bound, R13)

// ws layout in floats
#define WT0_OFF 0        // 67*64
#define B0_OFF  4288     // 64
#define WT1_OFF 4352     // 64*64
#define B1_OFF  8448     // 64
#define WT2_OFF 8512     // 64*128
#define B2_OFF  16704    // 128
#define PROG_OFF 16832   // 4 counters, 64-int (256B) spaced
#define STAGE_OFF 17088  // float4[NBATCH*NS] staging (16B aligned)

// shared-memory union offsets (bytes)
#define P_LCO 0          // producer: 8192 * float4 = 131072
#define P_CND 131072     // producer: 2*4*2 floats = 64
#define C_CAND 0         // consumer: 1024 * u64 = 8192
#define C_HA   8192      // 32*69*4 = 8832
#define C_HB   17024     // 32*65*4 = 8320
#define C_SEL  25344     // 32*4
#define C_CNT  25488     // 4
#define C_CXY  25504     // float4 (16B aligned)
#define SMEM_BYTES 131200

typedef float f32x2 __attribute__((ext_vector_type(2)));
typedef float f32x4 __attribute__((ext_vector_type(4)));

__device__ __forceinline__ float sq3(float ax, float ay, float az) {
  // exact f32, no contraction: (ax*ax + ay*ay) + az*az
  return __fadd_rn(__fadd_rn(__fmul_rn(ax, ax), __fmul_rn(ay, ay)), __fmul_rn(az, az));
}

// ---- cache-bypass (sc0 sc1 -> coherence point = L3/mem, shared across XCDs) ----
__device__ __forceinline__ void bypass_store128(void* p, f32x4 v) {
  asm volatile("global_store_dwordx4 %0, %1, off sc0 sc1" :: "v"(p), "v"(v) : "memory");
}
__device__ __forceinline__ f32x4 bypass_load128(const void* p) {
  f32x4 r;
  asm volatile("global_load_dwordx4 %0, %1, off sc0 sc1\n\ts_waitcnt vmcnt(0)"
               : "=v"(r) : "v"(p) : "memory");
  return r;
}
__device__ __forceinline__ void bypass_store32(void* p, int v) {
  asm volatile("global_store_dword %0, %1, off sc0 sc1" :: "v"(p), "v"(v) : "memory");
}
__device__ __forceinline__ int bypass_load32(const void* p) {
  int r;
  asm volatile("global_load_dword %0, %1, off sc0 sc1\n\ts_waitcnt vmcnt(0)"
               : "=v"(r) : "v"(p) : "memory");
  return r;
}

// packed 2xf32 ops (VOP3P, IEEE f32 per lane — exact, same as scalar __f*_rn)
__device__ __forceinline__ f32x2 pk_sub(f32x2 a, f32x2 b) {
  f32x2 r;
  asm("v_pk_add_f32 %0, %1, %2 neg_lo:[0,1] neg_hi:[0,1]" : "=v"(r) : "v"(a), "v"(b));
  return r;
}
__device__ __forceinline__ f32x2 pk_mul(f32x2 a, f32x2 b) {
  f32x2 r;
  asm("v_pk_mul_f32 %0, %1, %2" : "=v"(r) : "v"(a), "v"(b));
  return r;
}
__device__ __forceinline__ f32x2 pk_add(f32x2 a, f32x2 b) {
  f32x2 r;
  asm("v_pk_add_f32 %0, %1, %2" : "=v"(r) : "v"(a), "v"(b));
  return r;
}

// Lexicographic (max d, tie -> min idx) pair-combine with a DPP-shuffled copy.
#define PAIRRED(dv, iv, ctrl)                                                          \
  {                                                                                    \
    int _sd = __builtin_amdgcn_update_dpp(__float_as_int(dv), __float_as_int(dv),      \
                                          (ctrl), 0xf, 0xf, false);                    \
    int _si = __builtin_amdgcn_update_dpp((iv), (iv), (ctrl), 0xf, 0xf, false);        \
    float _fd = __int_as_float(_sd);                                                   \
    bool _tk = (_fd > (dv)) || ((_fd == (dv)) && (_si < (iv)));                        \
    (dv) = _tk ? _fd : (dv);                                                           \
    (iv) = _tk ? _si : (iv);                                                           \
  }

// ---------------- fold BN into weights (transposed [c][o]) ----------------
__global__ void fold_kernel(const float* __restrict__ W0, const float* __restrict__ g0, const float* __restrict__ be0, const float* __restrict__ m0, const float* __restrict__ v0,
                            const float* __restrict__ W1, const float* __restrict__ g1, const float* __restrict__ be1, const float* __restrict__ m1, const float* __restrict__ v1,
                            const float* __restrict__ W2, const float* __restrict__ g2, const float* __restrict__ be2, const float* __restrict__ m2, const float* __restrict__ v2,
                            float* __restrict__ ws) {
  int t = blockIdx.x * 256 + threadIdx.x;
  if (t < C0 * H1) {
    int c = t / H1, o = t - c * H1;
    float sc = g0[o] / sqrtf(v0[o] + 1e-5f);
    ws[WT0_OFF + t] = W0[o * C0 + c] * sc;
  } else if (t < B0_OFF + H1) {
    int o = t - B0_OFF;
    float sc = g0[o] / sqrtf(v0[o] + 1e-5f);
    ws[t] = be0[o] - m0[o] * sc;
  } else if (t < WT1_OFF + H1 * H2) {
    int t2 = t - WT1_OFF; int c = t2 / H2, o = t2 - c * H2;
    float sc = g1[o] / sqrtf(v1[o] + 1e-5f);
    ws[t] = W1[o * H1 + c] * sc;
  } else if (t < B1_OFF + H2) {
    int o = t - B1_OFF;
    float sc = g1[o] / sqrtf(v1[o] + 1e-5f);
    ws[t] = be1[o] - m1[o] * sc;
  } else if (t < WT2_OFF + H2 * H3) {
    int t2 = t - WT2_OFF; int c = t2 / H3, o = t2 - c * H3;
    float sc = g2[o] / sqrtf(v2[o] + 1e-5f);
    ws[t] = W2[o * H2 + c] * sc;
  } else if (t < B2_OFF + H3) {
    int o = t - B2_OFF;
    float sc = g2[o] / sqrtf(v2[o] + 1e-5f);
    ws[t] = be2[o] - m2[o] * sc;
  }
}

// ---------------- fused: blocks 0-3 = FPS producer, rest = SA consumers ----------------
__global__ __launch_bounds__(256, 1)
void fused_kernel(const float* __restrict__ xyz, const float* __restrict__ feat,
                  const float* __restrict__ ws, float* __restrict__ newxyz,
                  float* __restrict__ outf, int* __restrict__ prog,
                  f32x4* __restrict__ stage) {
  __shared__ __align__(16) char smem[SMEM_BYTES];
  const int blk = blockIdx.x;
  const int tid = threadIdx.x;
  const int lane = tid & 63;

  if (blk < NBATCH) {
    // =========================== PRODUCER (FPS) ===========================
    const int b = blk;
    const float* px = xyz + (size_t)b * NPTS * 3;
    const int wv = tid >> 6;   // 0..3
    float* lco = (float*)(smem + P_LCO);
    float (*cnd)[4][2] = (float(*)[4][2])(smem + P_CND);
    int* pb = prog + b * 64;   // 256B-spaced progress counter

    f32x2 X2[16], Y2[16], Z2[16], D2[16];
#pragma unroll
    for (int jj = 0; jj < 16; ++jj) {
      int p0 = tid * 32 + 2 * jj;
      float x0 = px[p0 * 3 + 0], y0 = px[p0 * 3 + 1], z0 = px[p0 * 3 + 2];
      float x1 = px[p0 * 3 + 3], y1 = px[p0 * 3 + 4], z1 = px[p0 * 3 + 5];
      X2[jj][0] = x0; X2[jj][1] = x1;
      Y2[jj][0] = y0; Y2[jj][1] = y1;
      Z2[jj][0] = z0; Z2[jj][1] = z1;
      D2[jj][0] = BIGF; D2[jj][1] = BIGF;
      *(float4*)&lco[(size_t)p0 * 4]       = make_float4(x0, y0, z0, 0.0f);
      *(float4*)&lco[(size_t)(p0 + 1) * 4] = make_float4(x1, y1, z1, 0.0f);
    }

    float cx = px[0], cy = px[1], cz = px[2];
    // wave-0 register capture slots (lane l holds centroid of iter with t&15==l)
    float sx = cx, sy = cy, sz = cz;   // lane 0 -> t=0 centroid
    if (tid == 0) {
      float* o = newxyz + (size_t)b * NS * 3;
      o[0] = cx; o[1] = cy; o[2] = cz;
    }
    __syncthreads();   // lco ready

    int par = 0;
    for (int t = 1; t < NS; ++t) {
      f32x2 cpx, cpy, cpz;
      cpx[0] = cx; cpx[1] = cx;
      cpy[0] = cy; cpy[1] = cy;
      cpz[0] = cz; cpz[1] = cz;
      float bd = -1.0f; int bi = 0;
#pragma unroll
      for (int jj = 0; jj < 16; ++jj) {
        f32x2 dx = pk_sub(X2[jj], cpx);
        f32x2 dy = pk_sub(Y2[jj], cpy);
        f32x2 dz = pk_sub(Z2[jj], cpz);
        f32x2 xx = pk_mul(dx, dx);
        f32x2 yy = pk_mul(dy, dy);
        f32x2 ss = pk_add(xx, yy);
        f32x2 zz = pk_mul(dz, dz);
        f32x2 dd = pk_add(ss, zz);
        float n0 = fminf(D2[jj][0], dd[0]);
        float n1 = fminf(D2[jj][1], dd[1]);
        D2[jj][0] = n0; D2[jj][1] = n1;
        bool g0 = n0 > bd;
        bd = g0 ? n0 : bd;
        bi = g0 ? (tid * 32 + 2 * jj) : bi;
        bool g1 = n1 > bd;
        bd = g1 ? n1 : bd;
        bi = g1 ? (tid * 32 + 2 * jj + 1) : bi;
      }
      PAIRRED(bd, bi, 0x121);
      PAIRRED(bd, bi, 0x122);
      PAIRRED(bd, bi, 0x124);
      PAIRRED(bd, bi, 0x128);
      PAIRRED(bd, bi, 0x142);
      PAIRRED(bd, bi, 0x143);   // lane63 = wave winner
      if (lane == 63) {
        cnd[par][wv][0] = bd;
        cnd[par][wv][1] = __int_as_float(bi);
      }
      __syncthreads();

      const int ci = lane & 3;
      f32x2 cc = *(const f32x2*)&cnd[par][ci][0];
      float pd = cc[0];
      int pi = __float_as_int(cc[1]);
      PAIRRED(pd, pi, 0x121);
      PAIRRED(pd, pi, 0x122);
      const int far = __builtin_amdgcn_readfirstlane(pi);
      float4 c4 = *(const float4*)&lco[(size_t)far * 4];
      cx = c4.x; cy = c4.y; cz = c4.z;
      if (tid == 0) {
        float* o = newxyz + ((size_t)b * NS + t) * 3;   // plain L2 stores (R9-proven)
        o[0] = cx; o[1] = cy; o[2] = cz;
      }
      if (wv == 0) {
        // capture into the matching lane's registers (2-3 VALU ops, no memory)
        bool cap = (lane < 16) && (lane == (t & 15));
        sx = cap ? cx : sx; sy = cap ? cy : sy; sz = cap ? cz : sz;
        if ((t & 15) == 15) {
          // LAGGED publish: cover the PREVIOUS interval (its stores were issued
          // 16 iters (~18us, ~43k cycles) ago -> certainly retired). No drain.
          if (lane == 0) bypass_store32(pb, t - 15);
          if (lane < 16) {
            f32x4 st; st[0] = sx; st[1] = sy; st[2] = sz; st[3] = 0.0f;
            bypass_store128(stage + (size_t)b * NS + (t - 15) + lane, st);
          }
        }
      }
      par ^= 1;
    }
    // final: drain all stage stores, then publish completion
    if (wv == 0) {
      asm volatile("s_waitcnt vmcnt(0)" ::: "memory");
      if (lane == 0) bypass_store32(pb, NS);
    }
  } else {
    // =========================== CONSUMERS (SA) ===========================
    unsigned long long* cand = (unsigned long long*)(smem + C_CAND);
    float* hA = (float*)(smem + C_HA);
    float* hB = (float*)(smem + C_HB);
    int* sel = (int*)(smem + C_SEL);
    int* cntp = (int*)(smem + C_CNT);
    float* cxyz = (float*)(smem + C_CXY);

    int seen = 0;

    // tile mapping g -> (b = g&3, s = g>>2): each consumer's batch is FIXED
    // (NCONS/4 pollers per prog line), batches consumed evenly as produced.
    for (int g = blk - NBATCH; g < NBATCH * NS; g += NCONS) {
      const int b = g & 3;
      const int s = g >> 2;
      const size_t srow = (size_t)b * NS + s;

      if (tid == 0) {
        *cntp = 0;
        if (seen <= s) {
          int pv;
          do {
            pv = bypass_load32(prog + b * 64);
            if (pv <= s) __builtin_amdgcn_s_sleep(32);
          } while (pv <= s);
          seen = pv;
        }
        f32x4 c4 = bypass_load128(stage + srow);
        cxyz[0] = c4[0]; cxyz[1] = c4[1]; cxyz[2] = c4[2];
      }
      __syncthreads();

      const float* px = xyz + (size_t)b * NPTS * 3;
      const float* pf = feat + (size_t)b * NPTS * CIN;
      const float cx = cxyz[0];
      const float cy = cxyz[1];
      const float cz = cxyz[2];

      // ---- phase A: ball query + ballot compaction ----
      const float ssrc = sq3(cx, cy, cz);
      const float R2F = 0.04f;  // f32 round of f64 0.2**2
      for (int p = tid; p < NPTS; p += 256) {
        float x = px[p * 3 + 0], y = px[p * 3 + 1], z = px[p * 3 + 2];
        float sdst = sq3(x, y, z);
        float dot = __fadd_rn(__fadd_rn(__fmul_rn(cx, x), __fmul_rn(cy, y)), __fmul_rn(cz, z));
        float d = __fsub_rn(__fadd_rn(ssrc, sdst), __fmul_rn(2.0f, dot));
        d = fmaxf(d, 0.0f);
        bool hit = (d <= R2F);
        unsigned long long m = __ballot(hit);
        if (m) {
          int base = 0;
          if (lane == 0) base = atomicAdd(cntp, __popcll(m));
          base = __shfl(base, 0);
          if (hit) {
            int pos = base + __popcll(m & ((1ull << lane) - 1ull));
            if (pos < CAP)
              cand[pos] = ((unsigned long long)__float_as_uint(d) << 32) | (unsigned long long)(unsigned)p;
          }
        }
      }
      __syncthreads();

      // ---- phase B: parallel rank-select of 32 smallest ----
      {
        const int cnt = min(*cntp, CAP);
        if (cnt <= 256) {
          unsigned long long k0 = (tid < cnt) ? cand[tid] : ~0ull;
          int r0 = 0;
          int j = 0;
          for (; j + 2 <= cnt; j += 2) {
            ulonglong2 kj = *(const ulonglong2*)&cand[j];
            r0 += (kj.x < k0) ? 1 : 0;
            r0 += (kj.y < k0) ? 1 : 0;
          }
          if (j < cnt) r0 += (cand[j] < k0) ? 1 : 0;
          if (tid < cnt) {
            if (r0 < NK) sel[r0] = (int)(k0 & 0xffffffffull);
            if (r0 == 0) {
              for (int q = cnt; q < NK; ++q) sel[q] = (int)(k0 & 0xffffffffull);
            }
          }
        } else if (cnt <= 512) {
          unsigned long long k0 = cand[tid];
          unsigned long long k1 = (256 + tid < cnt) ? cand[256 + tid] : ~0ull;
          int r0 = 0, r1 = 0;
          int j = 0;
          for (; j + 2 <= cnt; j += 2) {
            ulonglong2 kj = *(const ulonglong2*)&cand[j];
            r0 += (kj.x < k0) ? 1 : 0; r0 += (kj.y < k0) ? 1 : 0;
            r1 += (kj.x < k1) ? 1 : 0; r1 += (kj.y < k1) ? 1 : 0;
          }
          if (j < cnt) { unsigned long long kj = cand[j]; r0 += (kj < k0) ? 1 : 0; r1 += (kj < k1) ? 1 : 0; }
          if (r0 < NK) sel[r0] = (int)(k0 & 0xffffffffull);
          if (256 + tid < cnt && r1 < NK) sel[r1] = (int)(k1 & 0xffffffffull);
        } else {
          unsigned long long k0 = cand[tid];
          unsigned long long k1 = cand[256 + tid];
          unsigned long long k2 = (512 + tid < cnt) ? cand[512 + tid] : ~0ull;
          unsigned long long k3 = (768 + tid < cnt) ? cand[768 + tid] : ~0ull;
          int r0 = 0, r1 = 0, r2 = 0, r3 = 0;
          int j = 0;
          for (; j + 2 <= cnt; j += 2) {
            ulonglong2 kj = *(const ulonglong2*)&cand[j];
            r0 += (kj.x < k0) ? 1 : 0; r0 += (kj.y < k0) ? 1 : 0;
            r1 += (kj.x < k1) ? 1 : 0; r1 += (kj.y < k1) ? 1 : 0;
            r2 += (kj.x < k2) ? 1 : 0; r2 += (kj.y < k2) ? 1 : 0;
            r3 += (kj.x < k3) ? 1 : 0; r3 += (kj.y < k3) ? 1 : 0;
          }
          if (j < cnt) {
            unsigned long long kj = cand[j];
            r0 += (kj < k0) ? 1 : 0; r1 += (kj < k1) ? 1 : 0;
            r2 += (kj < k2) ? 1 : 0; r3 += (kj < k3) ? 1 : 0;
          }
          if (r0 < NK) sel[r0] = (int)(k0 & 0xffffffffull);
          if (r1 < NK) sel[r1] = (int)(k1 & 0xffffffffull);
          if (512 + tid < cnt && r2 < NK) sel[r2] = (int)(k2 & 0xffffffffull);
          if (768 + tid < cnt && r3 < NK) sel[r3] = (int)(k3 & 0xffffffffull);
        }
      }
      __syncthreads();

      // ---- phase C: build h0 = [centered xyz(3) | feat(64)] into hA [32][69] ----
      {
        int kk = tid >> 3, j = tid & 7;
        int ip = sel[kk];
        const float* fr = pf + (size_t)ip * CIN + j * 8;
        float4 a = *(const float4*)(fr);
        float4 c4 = *(const float4*)(fr + 4);
        float* hrow = hA + kk * 69 + 3 + j * 8;
        hrow[0] = a.x;  hrow[1] = a.y;  hrow[2] = a.z;  hrow[3] = a.w;
        hrow[4] = c4.x; hrow[5] = c4.y; hrow[6] = c4.z; hrow[7] = c4.w;
      }
      if (tid < 32) {
        int ip = sel[tid];
        hA[tid * 69 + 0] = px[ip * 3 + 0] - cx;
        hA[tid * 69 + 1] = px[ip * 3 + 1] - cy;
        hA[tid * 69 + 2] = px[ip * 3 + 2] - cz;
      }
      __syncthreads();

      const int k = tid & 31;
      const int ob = tid >> 5;

      // ---- layer 1: 67 -> 64 ----
      {
        const float* Wt = ws + WT0_OFF;
        const float* bb = ws + B0_OFF;
        const int o0 = ob * 8;
        float acc[8];
#pragma unroll
        for (int i = 0; i < 8; ++i) acc[i] = bb[o0 + i];
        const float* hrow = hA + k * 69;
        for (int c = 0; c < C0; ++c) {
          float h = hrow[c];
          const float4 w0 = *(const float4*)(Wt + c * H1 + o0);
          const float4 w1 = *(const float4*)(Wt + c * H1 + o0 + 4);
          acc[0] = fmaf(h, w0.x, acc[0]); acc[1] = fmaf(h, w0.y, acc[1]);
          acc[2] = fmaf(h, w0.z, acc[2]); acc[3] = fmaf(h, w0.w, acc[3]);
          acc[4] = fmaf(h, w1.x, acc[4]); acc[5] = fmaf(h, w1.y, acc[5]);
          acc[6] = fmaf(h, w1.z, acc[6]); acc[7] = fmaf(h, w1.w, acc[7]);
        }
        float* orow = hB + k * 65 + o0;
#pragma unroll
        for (int i = 0; i < 8; ++i) orow[i] = fmaxf(acc[i], 0.0f);
      }
      __syncthreads();

      // ---- layer 2: 64 -> 64 (hB -> hA, stride 65) ----
      {
        const float* Wt = ws + WT1_OFF;
        const float* bb = ws + B1_OFF;
        const int o0 = ob * 8;
        float acc[8];
#pragma unroll
        for (int i = 0; i < 8; ++i) acc[i] = bb[o0 + i];
        const float* hrow = hB + k * 65;
        for (int c = 0; c < H1; ++c) {
          float h = hrow[c];
          const float4 w0 = *(const float4*)(Wt + c * H2 + o0);
          const float4 w1 = *(const float4*)(Wt + c * H2 + o0 + 4);
          acc[0] = fmaf(h, w0.x, acc[0]); acc[1] = fmaf(h, w0.y, acc[1]);
          acc[2] = fmaf(h, w0.z, acc[2]); acc[3] = fmaf(h, w0.w, acc[3]);
          acc[4] = fmaf(h, w1.x, acc[4]); acc[5] = fmaf(h, w1.y, acc[5]);
          acc[6] = fmaf(h, w1.z, acc[6]); acc[7] = fmaf(h, w1.w, acc[7]);
        }
        float* orow = hA + k * 65 + o0;
#pragma unroll
        for (int i = 0; i < 8; ++i) orow[i] = fmaxf(acc[i], 0.0f);
      }
      __syncthreads();

      // ---- layer 3: 64 -> 128 + max over neighbors ----
      {
        const float* Wt = ws + WT2_OFF;
        const float* bb = ws + B2_OFF;
        const int o0 = ob * 16;
        float acc[16];
#pragma unroll
        for (int i = 0; i < 16; ++i) acc[i] = bb[o0 + i];
        const float* hrow = hA + k * 65;
        for (int c = 0; c < H2; ++c) {
          float h = hrow[c];
          const float4 w0 = *(const float4*)(Wt + c * H3 + o0);
          const float4 w1 = *(const float4*)(Wt + c * H3 + o0 + 4);
          const float4 w2 = *(const float4*)(Wt + c * H3 + o0 + 8);
          const float4 w3 = *(const float4*)(Wt + c * H3 + o0 + 12);
          acc[0]  = fmaf(h, w0.x, acc[0]);  acc[1]  = fmaf(h, w0.y, acc[1]);
          acc[2]  = fmaf(h, w0.z, acc[2]);  acc[3]  = fmaf(h, w0.w, acc[3]);
          acc[4]  = fmaf(h, w1.x, acc[4]);  acc[5]  = fmaf(h, w1.y, acc[5]);
          acc[6]  = fmaf(h, w1.z, acc[6]);  acc[7]  = fmaf(h, w1.w, acc[7]);
          acc[8]  = fmaf(h, w2.x, acc[8]);  acc[9]  = fmaf(h, w2.y, acc[9]);
          acc[10] = fmaf(h, w2.z, acc[10]); acc[11] = fmaf(h, w2.w, acc[11]);
          acc[12] = fmaf(h, w3.x, acc[12]); acc[13] = fmaf(h, w3.y, acc[13]);
          acc[14] = fmaf(h, w3.z, acc[14]); acc[15] = fmaf(h, w3.w, acc[15]);
        }
#pragma unroll
        for (int i = 0; i < 16; ++i) acc[i] = fmaxf(acc[i], 0.0f);
#pragma unroll
        for (int m = 1; m < 32; m <<= 1) {
#pragma unroll
          for (int i = 0; i < 16; ++i) {
            float o = __shfl_xor(acc[i], m);
            acc[i] = fmaxf(acc[i], o);
          }
        }
        if (k == 0) {
          float* op = outf + srow * H3 + o0;
          *(float4*)(op + 0)  = make_float4(acc[0],  acc[1],  acc[2],  acc[3]);
          *(float4*)(op + 4)  = make_float4(acc[4],  acc[5],  acc[6],  acc[7]);
          *(float4*)(op + 8)  = make_float4(acc[8],  acc[9],  acc[10], acc[11]);
          *(float4*)(op + 12) = make_float4(acc[12], acc[13], acc[14], acc[15]);
        }
      }
      __syncthreads();
    }
  }
}

extern "C" void kernel_launch(void* const* d_in, const int* in_sizes, int n_in,
                              void* d_out, int out_size, void* d_ws, size_t ws_size,
                              hipStream_t stream) {
  const float* xyz  = (const float*)d_in[0];
  const float* feat = (const float*)d_in[1];
  const float* W0 = (const float*)d_in[2];
  const float* g0 = (const float*)d_in[3];
  const float* be0 = (const float*)d_in[4];
  const float* m0 = (const float*)d_in[5];
  const float* v0 = (const float*)d_in[6];
  const float* W1 = (const float*)d_in[7];
  const float* g1 = (const float*)d_in[8];
  const float* be1 = (const float*)d_in[9];
  const float* m1 = (const float*)d_in[10];
  const float* v1 = (const float*)d_in[11];
  const float* W2 = (const float*)d_in[12];
  const float* g2 = (const float*)d_in[13];
  const float* be2 = (const float*)d_in[14];
  const float* m2 = (const float*)d_in[15];
  const float* v2 = (const float*)d_in[16];

  float* out = (float*)d_out;               // [B,S,3] then [B,S,128]
  float* wsf = (float*)d_ws;
  int* prog = (int*)(wsf + PROG_OFF);
  f32x4* stage = (f32x4*)(wsf + STAGE_OFF);
  float* outfeat = out + (size_t)NBATCH * NS * 3;

  fold_kernel<<<(B2_OFF + H3 + 255) / 256, 256, 0, stream>>>(
      W0, g0, be0, m0, v0, W1, g1, be1, m1, v1, W2, g2, be2, m2, v2, wsf);
  hipMemsetAsync(prog, 0, NBATCH * 64 * sizeof(int), stream);   // reset progress each launch
  fused_kernel<<<NBATCH + NCONS, 256, 0, stream>>>(xyz, feat, wsf, out, outfeat, prog, stage);
}